// Round 7
// baseline (241.201 us; speedup 1.0000x reference)
//
#include <hip/hip_runtime.h>

typedef float f32x4 __attribute__((ext_vector_type(4)));
typedef float f32x16 __attribute__((ext_vector_type(16)));
typedef __bf16 bf16x8 __attribute__((ext_vector_type(8)));
typedef unsigned short u16x8 __attribute__((ext_vector_type(8)));
typedef unsigned int u32x4 __attribute__((ext_vector_type(4)));

#define SCQ 0.1803368801111183f  // 0.125 * log2(e): softmax in exp2 domain

__device__ inline unsigned short f2bf(float f) {
  unsigned int u = __builtin_bit_cast(unsigned int, f);
  u += 0x7FFFu + ((u >> 16) & 1u);
  return (unsigned short)(u >> 16);
}

__device__ inline float fexp2(float x) {
#if __has_builtin(__builtin_amdgcn_exp2f)
  return __builtin_amdgcn_exp2f(x);
#else
  return exp2f(x);
#endif
}

// pack two f32 -> one dword of 2 bf16 (lo = a, hi = b), RNE
__device__ inline unsigned int cvtpk_bf16(float a, float b) {
  unsigned int r;
  __asm__("v_cvt_pk_bf16_f32 %0, %1, %2" : "=v"(r) : "v"(a), "v"(b));
  return r;
}
// swap a's upper 32 lanes with b's lower 32 lanes (both modified)
__device__ inline void permswap32(unsigned int& a, unsigned int& b) {
  __asm__("v_permlane32_swap_b32 %0, %1" : "+v"(a), "+v"(b));
}

__device__ inline void gload_lds16(const unsigned short* g, unsigned short* l) {
  __builtin_amdgcn_global_load_lds(
      (const __attribute__((address_space(1))) unsigned int*)g,
      (__attribute__((address_space(3))) unsigned int*)l, 16, 0, 0);
}

// ---------------- fp32 -> bf16 conversion (x + 4 weight matrices, one launch) ----
__global__ void cvt_all(const float* __restrict__ x,
                        const float* __restrict__ wq, const float* __restrict__ wk,
                        const float* __restrict__ wv, const float* __restrict__ wp,
                        unsigned short* __restrict__ xb,
                        unsigned short* __restrict__ oq, unsigned short* __restrict__ ok,
                        unsigned short* __restrict__ ov, unsigned short* __restrict__ op_) {
  int gid = blockIdx.x;
  const float* src;
  unsigned short* dst;
  int i;
  if (gid < 8192) {
    src = x; dst = xb;
    i = (gid * 256 + threadIdx.x) * 4;
  } else {
    int g = gid - 8192;
    int m = g >> 10;
    src = (m == 0) ? wq : (m == 1) ? wk : (m == 2) ? wv : wp;
    dst = (m == 0) ? oq : (m == 1) ? ok : (m == 2) ? ov : op_;
    i = ((g & 1023) * 256 + threadIdx.x) * 4;
  }
  float4 f = *(const float4*)(src + i);
  ushort4 o;
  o.x = f2bf(f.x); o.y = f2bf(f.y); o.z = f2bf(f.z); o.w = f2bf(f.w);
  *(ushort4*)(dst + i) = o;
}

// ---------------- QKV GEMM 256x256, 8-phase schedule (m201 template) ----------------
// out[m][n] = sum_k A[m][k]*Bt[n][k] + bias[n], N=3072 fused QKV.
// 512 threads = 8 waves (2x4); wave output 128x64 as 4 quadrants of 64x32.
// BK=64, 2 K-tiles double-buffered, LDS 128 KiB, regions {A0,A1,B0,B1} of 128x64.
// Staging stream g: tile=g>>2, half order {A0,B0,B1,A1} — each region's
// overwrite is issued >=1 barrier after that region's last read in the
// previous same-parity tile (A0 read ph0, staged ph1; B0 ph0->ph2; B1 ph1->ph3;
// A1 ph2 -> ph0 of next tile). vmcnt(6) once per K-tile (3 half-tiles = 6 loads
// in flight, 4-7 phases of latency cover); vmcnt(0) only at NT-2. (T2+T3+T4+T5)
// Grid: 1D 384, bm = wg&31 (m fastest) -> XCD=wg%8 owns a 4-m-block stripe
// (2 MiB A, L2-resident); B streams via LLC under the prefetch depth.
// (R3's contiguous-chunk swizzle made each XCD walk all of A: FETCH 103 MB.)
// Q/K blocks (bn<8): bf16 scatter [B,H,T,D], Q pre-scaled by SCQ.
// V blocks (bn>=8): fused transpose epilogue -> vt[bh][d][t] (replaces
// transpose_v kernel; acc -> 64KB LDS tile, XOR-swizzled, coalesced stores).
__global__ __launch_bounds__(512, 2) void gemm256qkv(const unsigned short* __restrict__ A,
                                                     const unsigned short* __restrict__ Bt,
                                                     const float* __restrict__ b0,
                                                     const float* __restrict__ b1,
                                                     const float* __restrict__ b2,
                                                     unsigned short* __restrict__ out,
                                                     unsigned short* __restrict__ vt,
                                                     int K) {
  __shared__ __align__(16) unsigned short Lg[2][4][128 * 64];
  const int tid = threadIdx.x;
  const int lane = tid & 63, w = tid >> 6;
  const int qm = w >> 2, qn = w & 3;       // wave position in the 128x128 quadrant grid
  const int l15 = lane & 15, kq = lane >> 4;

  const int wg = blockIdx.x;
  const int bm = wg & 31, bn = wg >> 5;    // m fastest: XCD = wg%8 -> A-stripe L2-local
  const int m0 = bm * 256, n0 = bn * 256;
  const int NT = K >> 6, NT4 = NT << 2;

  // staging constants: thread covers chunks tid, tid+512 of each 1024-chunk region
  const int row0 = tid >> 3, c0 = (tid & 7) ^ (row0 & 7);
  const int row1 = row0 + 64, c1 = (tid & 7) ^ (row1 & 7);
  const int ch0 = tid, ch1 = tid + 512;

  auto stage = [&](int g) {
    if (g < NT4) {
      const int tt = g >> 2, h = g & 3;
      const unsigned short* s_;
      int rbase, reg_;
      if (h == 0)      { s_ = A;  rbase = m0;       reg_ = 0; }
      else if (h == 3) { s_ = A;  rbase = m0 + 128; reg_ = 1; }
      else if (h == 1) { s_ = Bt; rbase = n0;       reg_ = 2; }
      else             { s_ = Bt; rbase = n0 + 128; reg_ = 3; }
      unsigned short* d = &Lg[tt & 1][reg_][0];
      gload_lds16(s_ + (size_t)(rbase + row0) * K + tt * 64 + c0 * 8, d + ch0 * 8);
      gload_lds16(s_ + (size_t)(rbase + row1) * K + tt * 64 + c1 * 8, d + ch1 * 8);
    }
  };

  auto rdAh = [&](const unsigned short* R, u16x8 (&a)[4][2]) {
#pragma unroll
    for (int mf = 0; mf < 4; mf++) {
      int row = qm * 64 + mf * 16 + l15;
#pragma unroll
      for (int kf = 0; kf < 2; kf++) {
        int pc = (kf * 4 + kq) ^ (row & 7);
        a[mf][kf] = *(const u16x8*)(R + row * 64 + pc * 8);
      }
    }
  };
  auto rdBh = [&](const unsigned short* R, u16x8 (&bb)[2][2]) {
#pragma unroll
    for (int nf = 0; nf < 2; nf++) {
      int row = qn * 32 + nf * 16 + l15;
#pragma unroll
      for (int kf = 0; kf < 2; kf++) {
        int pc = (kf * 4 + kq) ^ (row & 7);
        bb[nf][kf] = *(const u16x8*)(R + row * 64 + pc * 8);
      }
    }
  };
  auto domfma = [&](u16x8 (&a)[4][2], u16x8 (&bb)[2][2], f32x4 (*ac)[2]) {
#pragma unroll
    for (int mf = 0; mf < 4; mf++)
#pragma unroll
      for (int nf = 0; nf < 2; nf++)
#pragma unroll
        for (int kf = 0; kf < 2; kf++)
          ac[mf][nf] = __builtin_amdgcn_mfma_f32_16x16x32_bf16(
              __builtin_bit_cast(bf16x8, a[mf][kf]),
              __builtin_bit_cast(bf16x8, bb[nf][kf]), ac[mf][nf], 0, 0, 0);
  };

  f32x4 acc[4][4][2] = {};  // [quadrant][mf][nf]

  // prologue: tile0's 4 halves + tile1's first 3
#pragma unroll
  for (int g = 0; g < 7; ++g) stage(g);
  __asm__ __volatile__("s_waitcnt vmcnt(6)" ::: "memory");  // tile0 landed
  __builtin_amdgcn_s_barrier();

  for (int tt = 0; tt < NT; ++tt) {
    const unsigned short* A0r = &Lg[tt & 1][0][0];
    const unsigned short* A1r = &Lg[tt & 1][1][0];
    const unsigned short* B0r = &Lg[tt & 1][2][0];
    const unsigned short* B1r = &Lg[tt & 1][3][0];
    const int gb = 7 + 4 * tt;
    u16x8 aA[4][2], bb0[2][2], bb1[2][2];

    // phase 0: quadrant (0,0)
    rdAh(A0r, aA); rdBh(B0r, bb0);
    stage(gb + 0);
    __builtin_amdgcn_s_barrier();
    __asm__ __volatile__("s_waitcnt lgkmcnt(0)" ::: "memory");
    __builtin_amdgcn_sched_barrier(0);
    __builtin_amdgcn_s_setprio(1);
    domfma(aA, bb0, acc[0]);
    __builtin_amdgcn_s_setprio(0);
    __builtin_amdgcn_s_barrier();

    // phase 1: quadrant (0,1)
    rdBh(B1r, bb1);
    stage(gb + 1);
    __builtin_amdgcn_s_barrier();
    __asm__ __volatile__("s_waitcnt lgkmcnt(0)" ::: "memory");
    __builtin_amdgcn_sched_barrier(0);
    __builtin_amdgcn_s_setprio(1);
    domfma(aA, bb1, acc[1]);
    __builtin_amdgcn_s_setprio(0);
    __builtin_amdgcn_s_barrier();

    // phase 2: quadrant (1,0)
    rdAh(A1r, aA);
    stage(gb + 2);
    __builtin_amdgcn_s_barrier();
    __asm__ __volatile__("s_waitcnt lgkmcnt(0)" ::: "memory");
    __builtin_amdgcn_sched_barrier(0);
    __builtin_amdgcn_s_setprio(1);
    domfma(aA, bb0, acc[2]);
    __builtin_amdgcn_s_setprio(0);
    __builtin_amdgcn_s_barrier();

    // phase 3: quadrant (1,1) — all frags already in registers
    stage(gb + 3);
    __builtin_amdgcn_s_setprio(1);
    domfma(aA, bb1, acc[3]);
    __builtin_amdgcn_s_setprio(0);
    if (tt < NT - 2) {
      __asm__ __volatile__("s_waitcnt vmcnt(6)" ::: "memory");
    } else if (tt == NT - 2) {
      __asm__ __volatile__("s_waitcnt vmcnt(0)" ::: "memory");
    }
    __builtin_amdgcn_s_barrier();
  }

  if (n0 >= 2048) {
    // ---- V blocks: fused transpose -> vt[bh][d][t], two 128-d passes ----
    unsigned short* Ld = &Lg[0][0][0];  // [128][256] u16 = 64 KB
    const int bb_ = m0 >> 11, t0g = m0 & 2047;
    const int vbase = n0 - 2048;
#pragma unroll
    for (int dh = 0; dh < 2; dh++) {
      if (dh) __syncthreads();
#pragma unroll
      for (int ph = 0; ph < 2; ph++) {   // quadrant p = ph*2 + dh  (p&1 == dh)
        const int p = ph * 2 + dh;
#pragma unroll
        for (int nf = 0; nf < 2; nf++) {
          const int dl = qn * 32 + nf * 16 + l15;      // 0..127 within d-half
          const float bv = b2[vbase + dh * 128 + dl];
          const int swz = (dl & 31) << 2;
#pragma unroll
          for (int mf = 0; mf < 4; mf++) {
            f32x4 v4 = acc[p][mf][nf];
#pragma unroll
            for (int rp = 0; rp < 2; rp++) {
              const int tl = ph * 128 + qm * 64 + mf * 16 + kq * 4 + rp * 2;
              unsigned int pk = cvtpk_bf16(v4[rp * 2] + bv, v4[rp * 2 + 1] + bv);
              *(unsigned int*)&Ld[dl * 256 + (tl ^ swz)] = pk;  // tl even, swz bits>=2
            }
          }
        }
      }
      __syncthreads();
#pragma unroll
      for (int i = 0; i < 16; i++) {
        const int d = (tid >> 5) + (i & 7) * 16;                 // 0..127
        const int tb = (tid & 31) * 4 + (i >> 3) * 128;          // 0..255, 4-aligned
        ushort4 val = *(const ushort4*)&Ld[d * 256 + (tb ^ ((d & 31) << 2))];
        const int cl = vbase + dh * 128 + d;
        const int hh = cl >> 6, dd = cl & 63;
        *(ushort4*)(vt + ((size_t)((bb_ * 16 + hh) * 64 + dd)) * 2048 + t0g + tb) = val;
      }
    }
    return;
  }

  // ---- Q/K blocks: bf16 scatter [B,H,T,D]; C row = kq*4+r, col = l15 ----
#pragma unroll
  for (int p = 0; p < 4; p++) {
    const int rb = m0 + (p >> 1) * 128 + qm * 64 + kq * 4;
    const int cb = n0 + (p & 1) * 128 + qn * 32 + l15;
#pragma unroll
    for (int nf = 0; nf < 2; nf++) {
      const int col = cb + nf * 16;
      const int which = col >> 10, cl = col & 1023;
      const float bv = (which == 0) ? b0[cl] : b1[cl];
      const float sc = (which == 0) ? SCQ : 1.f;
      const int hh = cl >> 6, dd = cl & 63;
#pragma unroll
      for (int mf = 0; mf < 4; mf++) {
        f32x4 v4 = acc[p][mf][nf];
#pragma unroll
        for (int r = 0; r < 4; r++) {
          int row = rb + mf * 16 + r;
          int b = row >> 11, t = row & 2047;
          out[(size_t)which * 8388608 +
              ((size_t)((b * 16 + hh) * 2048 + t)) * 64 + dd] = f2bf((v4[r] + bv) * sc);
        }
      }
    }
  }
}

// ---------------- GEMM 128x256, counted-vmcnt schedule (proj) ----------------
__global__ __launch_bounds__(512, 2) void gemm8p(const unsigned short* __restrict__ A,
                                                 const unsigned short* __restrict__ Bt,
                                                 const float* __restrict__ b0,
                                                 void* __restrict__ out,
                                                 int M, int N, int K) {
  __shared__ __align__(16) unsigned short Lg[2][3][128 * 64];
  const int tid = threadIdx.x;
  const int lane = tid & 63, w = tid >> 6;
  const int qm = w >> 2, qn = w & 3;       // wave position: 2M x 4N
  const int l15 = lane & 15, kq = lane >> 4;
  const int m0 = blockIdx.x * 128, n0 = blockIdx.y * 256;
  const int NT = K >> 6;

  const int row0 = tid >> 3, c0 = (tid & 7) ^ (row0 & 7);
  const int row1 = row0 + 64, c1 = (tid & 7) ^ (row1 & 7);

  auto stage = [&](int tt, int h) {
    if (tt < NT) {
      const unsigned short* s_ = (h == 0) ? A : Bt;
      const int rbase = (h == 0) ? m0 : (h == 1 ? n0 : n0 + 128);
      unsigned short* d = &Lg[tt & 1][h][0];
      gload_lds16(s_ + (size_t)(rbase + row0) * K + tt * 64 + c0 * 8, d + (size_t)tid * 8);
      gload_lds16(s_ + (size_t)(rbase + row1) * K + tt * 64 + c1 * 8, d + (size_t)(tid + 512) * 8);
    }
  };

  auto rdA = [&](const unsigned short* R, u16x8 (&a)[4][2]) {
#pragma unroll
    for (int mf = 0; mf < 4; mf++) {
      int row = qm * 64 + mf * 16 + l15;
#pragma unroll
      for (int kf = 0; kf < 2; kf++) {
        int pc = (kf * 4 + kq) ^ (row & 7);
        a[mf][kf] = *(const u16x8*)(R + row * 64 + pc * 8);
      }
    }
  };
  auto rdB = [&](const unsigned short* R, u16x8 (&bb)[2][2]) {
#pragma unroll
    for (int nf = 0; nf < 2; nf++) {
      int row = qn * 32 + nf * 16 + l15;
#pragma unroll
      for (int kf = 0; kf < 2; kf++) {
        int pc = (kf * 4 + kq) ^ (row & 7);
        bb[nf][kf] = *(const u16x8*)(R + row * 64 + pc * 8);
      }
    }
  };

  f32x4 acc[4][4] = {};  // [mf][nfg], nfg = hb*2 + nf

  auto domfma = [&](u16x8 (&a)[4][2], u16x8 (&bb)[2][2], int hb) {
#pragma unroll
    for (int mf = 0; mf < 4; mf++)
#pragma unroll
      for (int nf = 0; nf < 2; nf++)
#pragma unroll
        for (int kf = 0; kf < 2; kf++)
          acc[mf][hb * 2 + nf] = __builtin_amdgcn_mfma_f32_16x16x32_bf16(
              __builtin_bit_cast(bf16x8, a[mf][kf]),
              __builtin_bit_cast(bf16x8, bb[nf][kf]), acc[mf][hb * 2 + nf], 0, 0, 0);
  };

  stage(0, 0); stage(0, 1); stage(0, 2); stage(1, 0); stage(1, 1);
  __asm__ __volatile__("s_waitcnt vmcnt(4)" ::: "memory");
  __builtin_amdgcn_s_barrier();

  for (int tt = 0; tt < NT; ++tt) {
    const unsigned short* Ar  = &Lg[tt & 1][0][0];
    const unsigned short* B0r = &Lg[tt & 1][1][0];
    const unsigned short* B1r = &Lg[tt & 1][2][0];
    u16x8 aA[4][2], bb[2][2];

    rdA(Ar, aA); rdB(B0r, bb);
    stage(tt + 1, 2);
    __builtin_amdgcn_s_barrier();
    __asm__ __volatile__("s_waitcnt lgkmcnt(0)" ::: "memory");
    __builtin_amdgcn_sched_barrier(0);
    __builtin_amdgcn_s_setprio(1);
    domfma(aA, bb, 0);
    __builtin_amdgcn_s_setprio(0);
    __builtin_amdgcn_s_barrier();

    rdB(B1r, bb);
    stage(tt + 2, 0); stage(tt + 2, 1);
    __builtin_amdgcn_s_barrier();
    __asm__ __volatile__("s_waitcnt lgkmcnt(0)" ::: "memory");
    __builtin_amdgcn_sched_barrier(0);
    __builtin_amdgcn_s_setprio(1);
    domfma(aA, bb, 1);
    __builtin_amdgcn_s_setprio(0);
    if (tt < NT - 2) {
      __asm__ __volatile__("s_waitcnt vmcnt(4)" ::: "memory");
    } else if (tt == NT - 2) {
      __asm__ __volatile__("s_waitcnt vmcnt(0)" ::: "memory");
    }
    __builtin_amdgcn_s_barrier();
  }

#pragma unroll
  for (int nfg = 0; nfg < 4; nfg++) {
    const int col = n0 + (nfg >> 1) * 128 + qn * 32 + (nfg & 1) * 16 + l15;
    float bv = b0[col];
#pragma unroll
    for (int mf = 0; mf < 4; mf++) {
      f32x4 v4 = acc[mf][nfg];
#pragma unroll
      for (int r = 0; r < 4; r++) {
        int row = m0 + qm * 64 + mf * 16 + kq * 4 + r;
        ((float*)out)[(size_t)row * N + col] = v4[r] + bv;
      }
    }
  }
}

// ---------------- Flash attention (causal), 32-row waves, in-register P ----------------
__global__ __launch_bounds__(256, 2) void attn_kernel(const unsigned short* __restrict__ Q,
                                                      const unsigned short* __restrict__ Km,
                                                      const unsigned short* __restrict__ Vt,
                                                      unsigned short* __restrict__ Y) {
  constexpr int T = 2048, D = 64;
  __shared__ __align__(16) unsigned short Ks[2][64 * 64];
  __shared__ __align__(16) unsigned short Vs[2][64 * 64];
  const int tid = threadIdx.x;
  const int lane = tid & 63, w = tid >> 6;
  const int l31 = lane & 31, half = lane >> 5;
  const int bh = blockIdx.x;  // XCD = bh % 8
  const int b = bh >> 4, h = bh & 15;
  const int p = blockIdx.y;   // 0..7
  const unsigned short* Qp = Q + (size_t)bh * T * D;
  const unsigned short* Kp = Km + (size_t)bh * T * D;
  const unsigned short* Vp = Vt + (size_t)bh * D * T;

  const int bch0 = (w * 2) * 64, bch1 = (w * 2 + 1) * 64;
  const int ch0 = bch0 + lane, ch1 = bch1 + lane;
  const int row0 = ch0 >> 3, c0 = (ch0 & 7) ^ (row0 & 7);
  const int row1 = ch1 >> 3, c1 = (ch1 & 7) ^ (row1 & 7);

  for (int phase = 0; phase < 2; ++phase) {
    const int jt = phase ? (63 - (p * 4 + w)) : (p * 4 + w);
    const int qt = jt * 32;
    const int nit = phase ? (32 - 2 * p) : (2 * p + 2);  // block-uniform
    const int qg = qt + l31;  // this lane's q column

    bf16x8 aq[4];
#pragma unroll
    for (int kc = 0; kc < 4; kc++)
      aq[kc] = *(const bf16x8*)(Qp + (size_t)qg * D + kc * 16 + half * 8);
    __asm__ __volatile__("" :: "v"(__builtin_bit_cast(f32x4, aq[0])),
                              "v"(__builtin_bit_cast(f32x4, aq[1])),
                              "v"(__builtin_bit_cast(f32x4, aq[2])),
                              "v"(__builtin_bit_cast(f32x4, aq[3])));

    f32x16 o0 = {}, o1 = {};  // Y^T accumulators, d-blocks 0/1
    float lsum = 0.f;

    gload_lds16(Kp + (size_t)row0 * 64 + c0 * 8, Ks[0] + bch0 * 8);
    gload_lds16(Kp + (size_t)row1 * 64 + c1 * 8, Ks[0] + bch1 * 8);
    gload_lds16(Vp + (size_t)row0 * T + c0 * 8, Vs[0] + bch0 * 8);
    gload_lds16(Vp + (size_t)row1 * T + c1 * 8, Vs[0] + bch1 * 8);

    int cur = 0;
    for (int it = 0; it < nit; ++it) {
      const int s0 = it * 64;
      if (it + 1 < nit) {  // block-uniform
        const int s1 = s0 + 64;
        unsigned short* kd = Ks[cur ^ 1];
        unsigned short* vd = Vs[cur ^ 1];
        gload_lds16(Kp + (size_t)(s1 + row0) * 64 + c0 * 8, kd + bch0 * 8);
        gload_lds16(Kp + (size_t)(s1 + row1) * 64 + c1 * 8, kd + bch1 * 8);
        gload_lds16(Vp + (size_t)row0 * T + s1 + c0 * 8, vd + bch0 * 8);
        gload_lds16(Vp + (size_t)row1 * T + s1 + c1 * 8, vd + bch1 * 8);
        __asm__ __volatile__("s_waitcnt vmcnt(4)" ::: "memory");
      } else {
        __asm__ __volatile__("s_waitcnt vmcnt(0)" ::: "memory");
      }
      __builtin_amdgcn_s_barrier();
      __builtin_amdgcn_sched_barrier(0);

      if (s0 <= qt + 31) {  // wave-uniform: skip fully-masked tiles
        const unsigned short* Kb_ = Ks[cur];
        const unsigned short* Vb_ = Vs[cur];

        f32x16 sacc0 = {}, sacc1 = {};
#pragma unroll
        for (int kc = 0; kc < 4; kc++) {
          int kr0 = l31;
          int cc0 = (kc * 2 + half) ^ (kr0 & 7);
          u16x8 k0 = *(const u16x8*)(Kb_ + kr0 * 64 + cc0 * 8);
          sacc0 = __builtin_amdgcn_mfma_f32_32x32x16_bf16(
              __builtin_bit_cast(bf16x8, k0), aq[kc], sacc0, 0, 0, 0);
          int kr1 = 32 + l31;
          int cc1 = (kc * 2 + half) ^ (kr1 & 7);
          u16x8 k1 = *(const u16x8*)(Kb_ + kr1 * 64 + cc1 * 8);
          sacc1 = __builtin_amdgcn_mfma_f32_32x32x16_bf16(
              __builtin_bit_cast(bf16x8, k1), aq[kc], sacc1, 0, 0, 0);
        }

        const bool full = (s0 + 63) <= qt;
        float e0_[16], e1_[16];
        if (full) {
#pragma unroll
          for (int r = 0; r < 16; r++) { e0_[r] = fexp2(sacc0[r]); lsum += e0_[r]; }
#pragma unroll
          for (int r = 0; r < 16; r++) { e1_[r] = fexp2(sacc1[r]); lsum += e1_[r]; }
        } else {
#pragma unroll
          for (int r = 0; r < 16; r++) {
            int sg = s0 + (r & 3) + 8 * (r >> 2) + 4 * half;
            float ex = fexp2(sacc0[r]);
            ex = (sg > qg) ? 0.f : ex;
            e0_[r] = ex; lsum += ex;
          }
#pragma unroll
          for (int r = 0; r < 16; r++) {
            int sg = s0 + 32 + (r & 3) + 8 * (r >> 2) + 4 * half;
            float ex = fexp2(sacc1[r]);
            ex = (sg > qg) ? 0.f : ex;
            e1_[r] = ex; lsum += ex;
          }
        }

        bf16x8 pf[4];
        auto pack2 = [&](const float* e_, int kbase) {
#pragma unroll
          for (int kl = 0; kl < 2; kl++) {
            int base = kl * 8;
            unsigned int a0 = cvtpk_bf16(e_[base + 0], e_[base + 1]);
            unsigned int b0v = cvtpk_bf16(e_[base + 4], e_[base + 5]);
            permswap32(a0, b0v);
            unsigned int a1 = cvtpk_bf16(e_[base + 2], e_[base + 3]);
            unsigned int b1v = cvtpk_bf16(e_[base + 6], e_[base + 7]);
            permswap32(a1, b1v);
            u32x4 t = {a0, a1, b0v, b1v};
            pf[kbase + kl] = __builtin_bit_cast(bf16x8, t);
          }
        };
        pack2(e0_, 0);
        pack2(e1_, 2);

#pragma unroll
        for (int kc = 0; kc < 4; kc++) {
          int vr0 = l31;
          int cc0 = (kc * 2 + half) ^ (vr0 & 7);
          u16x8 v0 = *(const u16x8*)(Vb_ + vr0 * 64 + cc0 * 8);
          o0 = __builtin_amdgcn_mfma_f32_32x32x16_bf16(
              __builtin_bit_cast(bf16x8, v0), pf[kc], o0, 0, 0, 0);
          int vr1 = 32 + l31;
          int cc1 = (kc * 2 + half) ^ (vr1 & 7);
          u16x8 v1 = *(const u16x8*)(Vb_ + vr1 * 64 + cc1 * 8);
          o1 = __builtin_amdgcn_mfma_f32_32x32x16_bf16(
              __builtin_bit_cast(bf16x8, v1), pf[kc], o1, 0, 0, 0);
        }
      }

      __builtin_amdgcn_sched_barrier(0);
      __builtin_amdgcn_s_barrier();
      cur ^= 1;
    }

    float tot = lsum + __shfl_xor(lsum, 32);
    float inv = 1.f / tot;
    unsigned short* Yrow = Y + ((size_t)(b * T + qg)) * 1024 + h * 64;
#pragma unroll
    for (int rp = 0; rp < 8; rp++) {
      int r = rp * 2;
      int d = (r & 3) + 8 * (r >> 2) + 4 * half;
      *(unsigned int*)(Yrow + d)      = cvtpk_bf16(o0[r] * inv, o0[r + 1] * inv);
      *(unsigned int*)(Yrow + 32 + d) = cvtpk_bf16(o1[r] * inv, o1[r + 1] * inv);
    }
  }
}

// ---------------- launch ----------------
extern "C" void kernel_launch(void* const* d_in, const int* in_sizes, int n_in,
                              void* d_out, int out_size, void* d_ws, size_t ws_size,
                              hipStream_t stream) {
  const float* x  = (const float*)d_in[0];
  const float* Wq = (const float*)d_in[1];
  const float* bq = (const float*)d_in[2];
  const float* Wk = (const float*)d_in[3];
  const float* bk = (const float*)d_in[4];
  const float* Wv = (const float*)d_in[5];
  const float* bv = (const float*)d_in[6];
  const float* Wp = (const float*)d_in[7];
  const float* bp = (const float*)d_in[8];

  char* ws = (char*)d_ws;
  unsigned short* xb  = (unsigned short*)(ws + 0);          // 16 MiB: x bf16; later Y
  unsigned short* wqb = (unsigned short*)(ws + 16777216);   // Wq,Wk,Wv contiguous = 3072x1024
  unsigned short* wkb = (unsigned short*)(ws + 18874368);
  unsigned short* wvb = (unsigned short*)(ws + 20971520);
  unsigned short* wpb = (unsigned short*)(ws + 23068672);
  unsigned short* Qb  = (unsigned short*)(ws + 25165824);   // Q,K contiguous, 16 MiB each
  unsigned short* Kb  = (unsigned short*)(ws + 41943040);
  unsigned short* Vtb = (unsigned short*)(ws + 58720256);   // Vt written by QKV epilogue
  unsigned short* Yb  = xb;  // x dead after fused QKV GEMM

  cvt_all<<<12288, 256, 0, stream>>>(x, Wq, Wk, Wv, Wp, xb, wqb, wkb, wvb, wpb);

  gemm256qkv<<<384, 512, 0, stream>>>(xb, wqb, bq, bk, bv, Qb, Vtb, 1024);

  attn_kernel<<<dim3(64, 8), 256, 0, stream>>>(Qb, Kb, Vtb, Yb);

  gemm8p<<<dim3(64, 4), 512, 0, stream>>>(Yb, wpb, bp, d_out, 8192, 1024, 1024);
}

// Round 8
// 235.768 us; speedup vs baseline: 1.0230x; 1.0230x over previous
//
#include <hip/hip_runtime.h>

typedef float f32x4 __attribute__((ext_vector_type(4)));
typedef float f32x16 __attribute__((ext_vector_type(16)));
typedef __bf16 bf16x8 __attribute__((ext_vector_type(8)));
typedef unsigned short u16x8 __attribute__((ext_vector_type(8)));
typedef unsigned int u32x4 __attribute__((ext_vector_type(4)));

#define SCQ 0.1803368801111183f  // 0.125 * log2(e): softmax in exp2 domain

__device__ inline unsigned short f2bf(float f) {
  unsigned int u = __builtin_bit_cast(unsigned int, f);
  u += 0x7FFFu + ((u >> 16) & 1u);
  return (unsigned short)(u >> 16);
}

__device__ inline float fexp2(float x) {
#if __has_builtin(__builtin_amdgcn_exp2f)
  return __builtin_amdgcn_exp2f(x);
#else
  return exp2f(x);
#endif
}

// pack two f32 -> one dword of 2 bf16 (lo = a, hi = b), RNE
__device__ inline unsigned int cvtpk_bf16(float a, float b) {
  unsigned int r;
  __asm__("v_cvt_pk_bf16_f32 %0, %1, %2" : "=v"(r) : "v"(a), "v"(b));
  return r;
}
// swap a's upper 32 lanes with b's lower 32 lanes (both modified)
__device__ inline void permswap32(unsigned int& a, unsigned int& b) {
  __asm__("v_permlane32_swap_b32 %0, %1" : "+v"(a), "+v"(b));
}

__device__ inline void gload_lds16(const unsigned short* g, unsigned short* l) {
  __builtin_amdgcn_global_load_lds(
      (const __attribute__((address_space(1))) unsigned int*)g,
      (__attribute__((address_space(3))) unsigned int*)l, 16, 0, 0);
}

// ---------------- fp32 -> bf16 conversion (x + 4 weight matrices, one launch) ----
__global__ void cvt_all(const float* __restrict__ x,
                        const float* __restrict__ wq, const float* __restrict__ wk,
                        const float* __restrict__ wv, const float* __restrict__ wp,
                        unsigned short* __restrict__ xb,
                        unsigned short* __restrict__ oq, unsigned short* __restrict__ ok,
                        unsigned short* __restrict__ ov, unsigned short* __restrict__ op_) {
  int gid = blockIdx.x;
  const float* src;
  unsigned short* dst;
  int i;
  if (gid < 8192) {
    src = x; dst = xb;
    i = (gid * 256 + threadIdx.x) * 4;
  } else {
    int g = gid - 8192;
    int m = g >> 10;
    src = (m == 0) ? wq : (m == 1) ? wk : (m == 2) ? wv : wp;
    dst = (m == 0) ? oq : (m == 1) ? ok : (m == 2) ? ov : op_;
    i = ((g & 1023) * 256 + threadIdx.x) * 4;
  }
  float4 f = *(const float4*)(src + i);
  ushort4 o;
  o.x = f2bf(f.x); o.y = f2bf(f.y); o.z = f2bf(f.z); o.w = f2bf(f.w);
  *(ushort4*)(dst + i) = o;
}

// ---------------- GEMM 128x128 (m97 structure), fused V-transpose epilogue ----------
// out[m][n] = sum_k A[m][k]*Bt[n][k] + bias[n]. 256 thr = 4 waves, 64x64/wave,
// 2x2 of 32x32x16 MFMA, BK=64, global_load_lds w16, chunk-XOR swizzle.
// MODE 0 (fused QKV, N=3072): which=col>>10 -> {Q,K,V}.
//   Q: pre-scaled by SCQ, bf16 scatter [B,H,T,D] into out; K same (no scale).
//   V (n0>=2048, block-uniform): accumulators routed through the dead 32 KB
//   staging LDS as an XOR-swizzled [d][t] tile, then stored TRANSPOSED to
//   vt[bh][d][t] with coalesced 256-B segments — replaces the transpose_v
//   kernel entirely (saves a kernel + 64 MB of HBM round-trip).
// MODE 1: fp32 row-major MxN with bias b0.
template <int MODE>
__global__ __launch_bounds__(256) void gemm128(const unsigned short* __restrict__ A,
                                               const unsigned short* __restrict__ Bt,
                                               const float* __restrict__ b0,
                                               const float* __restrict__ b1,
                                               const float* __restrict__ b2,
                                               void* __restrict__ out,
                                               unsigned short* __restrict__ vt,
                                               int M, int N, int K) {
  __shared__ __align__(16) unsigned short Sh[2][128 * 64];
  unsigned short* As = Sh[0];
  unsigned short* Bs = Sh[1];
  const int tid = threadIdx.x;
  const int lane = tid & 63, w = tid >> 6;
  const int l31 = lane & 31, half = lane >> 5;
  const int wm = w & 1, wn = w >> 1;
  const int m0 = blockIdx.x * 128, n0 = blockIdx.y * 128;

  f32x16 acc[2][2] = {};

  for (int kb = 0; kb < K; kb += 64) {
#pragma unroll
    for (int j = 0; j < 4; j++) {
      int ch = j * 256 + w * 64 + lane;
      int row = ch >> 3, pc = ch & 7;
      int c = pc ^ (row & 7);
      gload_lds16(A + (size_t)(m0 + row) * K + kb + c * 8, As + (size_t)(j * 256 + w * 64) * 8);
      gload_lds16(Bt + (size_t)(n0 + row) * K + kb + c * 8, Bs + (size_t)(j * 256 + w * 64) * 8);
    }
    __syncthreads();
#pragma unroll
    for (int ks = 0; ks < 64; ks += 16) {
      bf16x8 af[2], bfr[2];
#pragma unroll
      for (int at = 0; at < 2; at++) {
        int row = wm * 64 + at * 32 + l31;
        int pc = ((ks >> 3) + half) ^ (row & 7);
        af[at] = *(const bf16x8*)(As + row * 64 + pc * 8);
      }
#pragma unroll
      for (int nt = 0; nt < 2; nt++) {
        int row = wn * 64 + nt * 32 + l31;
        int pc = ((ks >> 3) + half) ^ (row & 7);
        bfr[nt] = *(const bf16x8*)(Bs + row * 64 + pc * 8);
      }
#pragma unroll
      for (int at = 0; at < 2; at++)
#pragma unroll
        for (int nt = 0; nt < 2; nt++)
          acc[at][nt] = __builtin_amdgcn_mfma_f32_32x32x16_bf16(af[at], bfr[nt], acc[at][nt], 0, 0, 0);
    }
    __syncthreads();
  }

  if (MODE == 0 && n0 >= 2048) {
    // ---- V: LDS transpose + coalesced Vt store ----
    unsigned short* Lt = &Sh[0][0];  // 128 x 128 u16 = 32 KB (staging LDS, dead)
#pragma unroll
    for (int at = 0; at < 2; at++)
#pragma unroll
      for (int nt = 0; nt < 2; nt++) {
        int d = wn * 64 + nt * 32 + l31;          // d_local in [0,128)
        float bv = b2[(n0 & 1023) + d];
        int swz = (d & 31) << 2;                  // bank-spread XOR, bijective in t
#pragma unroll
        for (int reg = 0; reg < 16; reg++) {
          int t = wm * 64 + at * 32 + (reg & 3) + 8 * (reg >> 2) + 4 * half;
          Lt[d * 128 + (t ^ swz)] = f2bf(acc[at][nt][reg] + bv);
        }
      }
    __syncthreads();
    const int bb = m0 >> 11, t0 = m0 & 2047;
#pragma unroll
    for (int i = 0; i < 16; i++) {
      int d = (tid >> 5) + i * 8;
      int tb = (tid & 31) * 4;
      ushort4 val = *(const ushort4*)&Lt[d * 128 + (tb ^ ((d & 31) << 2))];
      int h = ((n0 & 1023) + d) >> 6;
      *(ushort4*)(vt + ((size_t)((bb * 16 + h) * 64 + (d & 63))) * 2048 + t0 + tb) = val;
    }
    return;
  }

#pragma unroll
  for (int at = 0; at < 2; at++)
#pragma unroll
    for (int nt = 0; nt < 2; nt++) {
      int col = n0 + wn * 64 + nt * 32 + l31;
      float bv, sc;
      int which = 0, cl = col;
      if (MODE == 0) {
        which = col >> 10; cl = col & 1023;
        const float* bp = (which == 0) ? b0 : b1;
        bv = bp[cl];
        sc = (which == 0) ? SCQ : 1.f;
      } else {
        bv = b0[col]; sc = 1.f;
      }
#pragma unroll
      for (int reg = 0; reg < 16; reg++) {
        int row = m0 + wm * 64 + at * 32 + (reg & 3) + 8 * (reg >> 2) + 4 * half;
        float v = (acc[at][nt][reg] + bv) * sc;
        if (MODE == 0) {
          int h = cl >> 6, d = cl & 63;
          int b = row >> 11, t = row & 2047;
          ((unsigned short*)out)[(size_t)which * 8388608 +
                                 ((size_t)((b * 16 + h) * 2048 + t)) * 64 + d] = f2bf(v);
        } else {
          ((float*)out)[(size_t)row * N + col] = v;
        }
      }
    }
}

// ---------------- GEMM 128x256, counted-vmcnt schedule (proj) ----------------
__global__ __launch_bounds__(512, 2) void gemm8p(const unsigned short* __restrict__ A,
                                                 const unsigned short* __restrict__ Bt,
                                                 const float* __restrict__ b0,
                                                 void* __restrict__ out,
                                                 int M, int N, int K) {
  __shared__ __align__(16) unsigned short Lg[2][3][128 * 64];
  const int tid = threadIdx.x;
  const int lane = tid & 63, w = tid >> 6;
  const int qm = w >> 2, qn = w & 3;       // wave position: 2M x 4N
  const int l15 = lane & 15, kq = lane >> 4;
  const int m0 = blockIdx.x * 128, n0 = blockIdx.y * 256;
  const int NT = K >> 6;

  const int row0 = tid >> 3, c0 = (tid & 7) ^ (row0 & 7);
  const int row1 = row0 + 64, c1 = (tid & 7) ^ (row1 & 7);

  auto stage = [&](int tt, int h) {
    if (tt < NT) {
      const unsigned short* s_ = (h == 0) ? A : Bt;
      const int rbase = (h == 0) ? m0 : (h == 1 ? n0 : n0 + 128);
      unsigned short* d = &Lg[tt & 1][h][0];
      gload_lds16(s_ + (size_t)(rbase + row0) * K + tt * 64 + c0 * 8, d + (size_t)tid * 8);
      gload_lds16(s_ + (size_t)(rbase + row1) * K + tt * 64 + c1 * 8, d + (size_t)(tid + 512) * 8);
    }
  };

  auto rdA = [&](const unsigned short* R, u16x8 (&a)[4][2]) {
#pragma unroll
    for (int mf = 0; mf < 4; mf++) {
      int row = qm * 64 + mf * 16 + l15;
#pragma unroll
      for (int kf = 0; kf < 2; kf++) {
        int pc = (kf * 4 + kq) ^ (row & 7);
        a[mf][kf] = *(const u16x8*)(R + row * 64 + pc * 8);
      }
    }
  };
  auto rdB = [&](const unsigned short* R, u16x8 (&bb)[2][2]) {
#pragma unroll
    for (int nf = 0; nf < 2; nf++) {
      int row = qn * 32 + nf * 16 + l15;
#pragma unroll
      for (int kf = 0; kf < 2; kf++) {
        int pc = (kf * 4 + kq) ^ (row & 7);
        bb[nf][kf] = *(const u16x8*)(R + row * 64 + pc * 8);
      }
    }
  };

  f32x4 acc[4][4] = {};  // [mf][nfg], nfg = hb*2 + nf

  auto domfma = [&](u16x8 (&a)[4][2], u16x8 (&bb)[2][2], int hb) {
#pragma unroll
    for (int mf = 0; mf < 4; mf++)
#pragma unroll
      for (int nf = 0; nf < 2; nf++)
#pragma unroll
        for (int kf = 0; kf < 2; kf++)
          acc[mf][hb * 2 + nf] = __builtin_amdgcn_mfma_f32_16x16x32_bf16(
              __builtin_bit_cast(bf16x8, a[mf][kf]),
              __builtin_bit_cast(bf16x8, bb[nf][kf]), acc[mf][hb * 2 + nf], 0, 0, 0);
  };

  stage(0, 0); stage(0, 1); stage(0, 2); stage(1, 0); stage(1, 1);
  __asm__ __volatile__("s_waitcnt vmcnt(4)" ::: "memory");
  __builtin_amdgcn_s_barrier();

  for (int tt = 0; tt < NT; ++tt) {
    const unsigned short* Ar  = &Lg[tt & 1][0][0];
    const unsigned short* B0r = &Lg[tt & 1][1][0];
    const unsigned short* B1r = &Lg[tt & 1][2][0];
    u16x8 aA[4][2], bb[2][2];

    rdA(Ar, aA); rdB(B0r, bb);
    stage(tt + 1, 2);
    __builtin_amdgcn_s_barrier();
    __asm__ __volatile__("s_waitcnt lgkmcnt(0)" ::: "memory");
    __builtin_amdgcn_sched_barrier(0);
    __builtin_amdgcn_s_setprio(1);
    domfma(aA, bb, 0);
    __builtin_amdgcn_s_setprio(0);
    __builtin_amdgcn_s_barrier();

    rdB(B1r, bb);
    stage(tt + 2, 0); stage(tt + 2, 1);
    __builtin_amdgcn_s_barrier();
    __asm__ __volatile__("s_waitcnt lgkmcnt(0)" ::: "memory");
    __builtin_amdgcn_sched_barrier(0);
    __builtin_amdgcn_s_setprio(1);
    domfma(aA, bb, 1);
    __builtin_amdgcn_s_setprio(0);
    if (tt < NT - 2) {
      __asm__ __volatile__("s_waitcnt vmcnt(4)" ::: "memory");
    } else if (tt == NT - 2) {
      __asm__ __volatile__("s_waitcnt vmcnt(0)" ::: "memory");
    }
    __builtin_amdgcn_s_barrier();
  }

#pragma unroll
  for (int nfg = 0; nfg < 4; nfg++) {
    const int col = n0 + (nfg >> 1) * 128 + qn * 32 + (nfg & 1) * 16 + l15;
    float bv = b0[col];
#pragma unroll
    for (int mf = 0; mf < 4; mf++) {
      f32x4 v4 = acc[mf][nfg];
#pragma unroll
      for (int r = 0; r < 4; r++) {
        int row = m0 + qm * 64 + mf * 16 + kq * 4 + r;
        ((float*)out)[(size_t)row * N + col] = v4[r] + bv;
      }
    }
  }
}

// ---------------- Flash attention (causal), 32-row waves, in-register P --------------
// Swapped-operand (T12) as before; NEW: KVBLK = 128 processed as 2x64 sub-tiles
// that REUSE the same sacc/e registers (no VGPR growth). Halves the barrier
// count (34 -> 17 iterations) — the R8 theory is that the per-iteration
// all-wave barrier+vmcnt rendezvous (at only 2 waves/SIMD TLP) was ~85% stall.
// LDS 64 KB (2 blocks/CU). Staging: 8 gloads/wave/iter, counted vmcnt(8)
// one tile ahead (~2 sub-compute phases of latency cover). Numerics: identical
// accumulation order to the 64-wide version (sub0 then sub1 = same s order).
// Iteration counts block-uniform: phase0 nit = p+1, phase1 nit = 16-p.
__global__ __launch_bounds__(256, 2) void attn_kernel(const unsigned short* __restrict__ Q,
                                                      const unsigned short* __restrict__ Km,
                                                      const unsigned short* __restrict__ Vt,
                                                      unsigned short* __restrict__ Y) {
  constexpr int T = 2048, D = 64;
  __shared__ __align__(16) unsigned short Ks[2][128 * 64];  // [s 0..127][d 0..63]
  __shared__ __align__(16) unsigned short Vs[2][64 * 128];  // [d 0..63][s 0..127]
  const int tid = threadIdx.x;
  const int lane = tid & 63, w = tid >> 6;
  const int l31 = lane & 31, half = lane >> 5;
  const int bh = blockIdx.x;  // XCD = bh % 8
  const int b = bh >> 4, h = bh & 15;
  const int p = blockIdx.y;   // 0..7
  const unsigned short* Qp = Q + (size_t)bh * T * D;
  const unsigned short* Kp = Km + (size_t)bh * T * D;
  const unsigned short* Vp = Vt + (size_t)bh * D * T;

  // staging constants: wave w covers chunks [w*256, w*256+255] via 4 gloads each
  // for K and V. K chunk ch: row = ch>>3 (0..127), c = (ch&7)^(row&7).
  // V chunk ch: d = ch>>4 (0..63), pcol = ch&15 (16B cols), c = pcol^(d&7)
  // (XOR affects low 3 bits only — bijective within the 16-chunk row).
  int krow[4], kc_[4], vd_[4], vc_[4];
#pragma unroll
  for (int q = 0; q < 4; q++) {
    int ch = w * 256 + q * 64 + lane;
    krow[q] = ch >> 3; kc_[q] = (ch & 7) ^ (krow[q] & 7);
    vd_[q] = ch >> 4;  vc_[q] = (ch & 15) ^ (vd_[q] & 7);
  }
  const int chb = w * 256;

  for (int phase = 0; phase < 2; ++phase) {
    const int jt = phase ? (63 - (p * 4 + w)) : (p * 4 + w);
    const int qt = jt * 32;
    const int nit = phase ? (16 - p) : (p + 1);  // block-uniform (128-wide tiles)
    const int qg = qt + l31;  // this lane's q column

    bf16x8 aq[4];
#pragma unroll
    for (int kc = 0; kc < 4; kc++)
      aq[kc] = *(const bf16x8*)(Qp + (size_t)qg * D + kc * 16 + half * 8);
    __asm__ __volatile__("" :: "v"(__builtin_bit_cast(f32x4, aq[0])),
                              "v"(__builtin_bit_cast(f32x4, aq[1])),
                              "v"(__builtin_bit_cast(f32x4, aq[2])),
                              "v"(__builtin_bit_cast(f32x4, aq[3])));

    f32x16 o0 = {}, o1 = {};  // Y^T accumulators, d-blocks 0/1
    float lsum = 0.f;

    // prologue: stage s-tile 0 (128 wide) into buffer 0
#pragma unroll
    for (int q = 0; q < 4; q++) {
      gload_lds16(Kp + (size_t)krow[q] * 64 + kc_[q] * 8, Ks[0] + (size_t)(chb + q * 64) * 8);
      gload_lds16(Vp + (size_t)vd_[q] * T + vc_[q] * 8, Vs[0] + (size_t)(chb + q * 64) * 8);
    }

    int cur = 0;
    for (int it = 0; it < nit; ++it) {
      const int s0 = it * 128;
      if (it + 1 < nit) {  // block-uniform
        const int s1 = s0 + 128;
        unsigned short* kd = Ks[cur ^ 1];
        unsigned short* vd = Vs[cur ^ 1];
#pragma unroll
        for (int q = 0; q < 4; q++) {
          gload_lds16(Kp + (size_t)(s1 + krow[q]) * 64 + kc_[q] * 8, kd + (size_t)(chb + q * 64) * 8);
          gload_lds16(Vp + (size_t)vd_[q] * T + s1 + vc_[q] * 8, vd + (size_t)(chb + q * 64) * 8);
        }
        __asm__ __volatile__("s_waitcnt vmcnt(8)" ::: "memory");
      } else {
        __asm__ __volatile__("s_waitcnt vmcnt(0)" ::: "memory");
      }
      __builtin_amdgcn_s_barrier();
      __builtin_amdgcn_sched_barrier(0);

      const unsigned short* Kb_ = Ks[cur];
      const unsigned short* Vb_ = Vs[cur];

#pragma unroll
      for (int sub = 0; sub < 2; sub++) {
        const int s0s = s0 + sub * 64;
        if (s0s <= qt + 31) {  // wave-uniform: skip fully-masked sub-tiles
          // ---- S^T = K . Q^T : two 32-s blocks (rows sub*64 + {0,32} + l31) ----
          f32x16 sacc0 = {}, sacc1 = {};
#pragma unroll
          for (int kc = 0; kc < 4; kc++) {
            int kr0 = sub * 64 + l31;
            int cc0 = (kc * 2 + half) ^ (kr0 & 7);
            u16x8 k0 = *(const u16x8*)(Kb_ + kr0 * 64 + cc0 * 8);
            sacc0 = __builtin_amdgcn_mfma_f32_32x32x16_bf16(
                __builtin_bit_cast(bf16x8, k0), aq[kc], sacc0, 0, 0, 0);
            int kr1 = sub * 64 + 32 + l31;
            int cc1 = (kc * 2 + half) ^ (kr1 & 7);
            u16x8 k1 = *(const u16x8*)(Kb_ + kr1 * 64 + cc1 * 8);
            sacc1 = __builtin_amdgcn_mfma_f32_32x32x16_bf16(
                __builtin_bit_cast(bf16x8, k1), aq[kc], sacc1, 0, 0, 0);
          }

          // ---- exp2 + causal mask + denominator ----
          const bool full = (s0s + 63) <= qt;
          float e0_[16], e1_[16];
          if (full) {
#pragma unroll
            for (int r = 0; r < 16; r++) { e0_[r] = fexp2(sacc0[r]); lsum += e0_[r]; }
#pragma unroll
            for (int r = 0; r < 16; r++) { e1_[r] = fexp2(sacc1[r]); lsum += e1_[r]; }
          } else {
#pragma unroll
            for (int r = 0; r < 16; r++) {
              int sg = s0s + (r & 3) + 8 * (r >> 2) + 4 * half;
              float ex = fexp2(sacc0[r]);
              ex = (sg > qg) ? 0.f : ex;
              e0_[r] = ex; lsum += ex;
            }
#pragma unroll
            for (int r = 0; r < 16; r++) {
              int sg = s0s + 32 + (r & 3) + 8 * (r >> 2) + 4 * half;
              float ex = fexp2(sacc1[r]);
              ex = (sg > qg) ? 0.f : ex;
              e1_[r] = ex; lsum += ex;
            }
          }

          // ---- build P^T B-fragments in-register (T12) ----
          bf16x8 pf[4];
          auto pack2 = [&](const float* e_, int kbase) {
#pragma unroll
            for (int kl = 0; kl < 2; kl++) {
              int base = kl * 8;
              unsigned int a0 = cvtpk_bf16(e_[base + 0], e_[base + 1]);
              unsigned int b0v = cvtpk_bf16(e_[base + 4], e_[base + 5]);
              permswap32(a0, b0v);
              unsigned int a1 = cvtpk_bf16(e_[base + 2], e_[base + 3]);
              unsigned int b1v = cvtpk_bf16(e_[base + 6], e_[base + 7]);
              permswap32(a1, b1v);
              u32x4 t = {a0, a1, b0v, b1v};
              pf[kbase + kl] = __builtin_bit_cast(bf16x8, t);
            }
          };
          pack2(e0_, 0);
          pack2(e1_, 2);

          // ---- Y^T += V^T . P^T : two 32-d blocks; s-chunk = sub*8 + kc*2 + half
#pragma unroll
          for (int kc = 0; kc < 4; kc++) {
            int sch = sub * 8 + kc * 2 + half;
            int vr0 = l31;
            int cc0 = sch ^ (vr0 & 7);
            u16x8 v0 = *(const u16x8*)(Vb_ + vr0 * 128 + cc0 * 8);
            o0 = __builtin_amdgcn_mfma_f32_32x32x16_bf16(
                __builtin_bit_cast(bf16x8, v0), pf[kc], o0, 0, 0, 0);
            int vr1 = 32 + l31;
            int cc1 = sch ^ (vr1 & 7);
            u16x8 v1 = *(const u16x8*)(Vb_ + vr1 * 128 + cc1 * 8);
            o1 = __builtin_amdgcn_mfma_f32_32x32x16_bf16(
                __builtin_bit_cast(bf16x8, v1), pf[kc], o1, 0, 0, 0);
          }
        }
      }

      __builtin_amdgcn_sched_barrier(0);
      __builtin_amdgcn_s_barrier();
      cur ^= 1;
    }

    float tot = lsum + __shfl_xor(lsum, 32);
    float inv = 1.f / tot;
    unsigned short* Yrow = Y + ((size_t)(b * T + qg)) * 1024 + h * 64;
#pragma unroll
    for (int rp = 0; rp < 8; rp++) {
      int r = rp * 2;
      int d = (r & 3) + 8 * (r >> 2) + 4 * half;
      *(unsigned int*)(Yrow + d)      = cvtpk_bf16(o0[r] * inv, o0[r + 1] * inv);
      *(unsigned int*)(Yrow + 32 + d) = cvtpk_bf16(o1[r] * inv, o1[r + 1] * inv);
    }
  }
}

// ---------------- launch ----------------
extern "C" void kernel_launch(void* const* d_in, const int* in_sizes, int n_in,
                              void* d_out, int out_size, void* d_ws, size_t ws_size,
                              hipStream_t stream) {
  const float* x  = (const float*)d_in[0];
  const float* Wq = (const float*)d_in[1];
  const float* bq = (const float*)d_in[2];
  const float* Wk = (const float*)d_in[3];
  const float* bk = (const float*)d_in[4];
  const float* Wv = (const float*)d_in[5];
  const float* bv = (const float*)d_in[6];
  const float* Wp = (const float*)d_in[7];
  const float* bp = (const float*)d_in[8];

  char* ws = (char*)d_ws;
  unsigned short* xb  = (unsigned short*)(ws + 0);          // 16 MiB: x bf16; later Y
  unsigned short* wqb = (unsigned short*)(ws + 16777216);   // Wq,Wk,Wv contiguous = 3072x1024
  unsigned short* wkb = (unsigned short*)(ws + 18874368);
  unsigned short* wvb = (unsigned short*)(ws + 20971520);
  unsigned short* wpb = (unsigned short*)(ws + 23068672);
  unsigned short* Qb  = (unsigned short*)(ws + 25165824);   // Q,K contiguous, 16 MiB each
  unsigned short* Kb  = (unsigned short*)(ws + 41943040);
  unsigned short* Vtb = (unsigned short*)(ws + 58720256);   // Vt written by QKV epilogue
  unsigned short* Yb  = xb;  // x dead after fused QKV GEMM

  cvt_all<<<12288, 256, 0, stream>>>(x, Wq, Wk, Wv, Wp, xb, wqb, wkb, wvb, wpb);

  gemm128<0><<<dim3(64, 24), 256, 0, stream>>>(xb, wqb, bq, bk, bv, Qb, Vtb, 8192, 3072, 1024);

  attn_kernel<<<dim3(64, 8), 256, 0, stream>>>(Qb, Kb, Vtb, Yb);

  gemm8p<<<dim3(64, 4), 512, 0, stream>>>(Yb, wpb, bp, d_out, 8192, 1024, 1024);
}